// Round 1
// baseline (4153.622 us; speedup 1.0000x reference)
//
#include <hip/hip_runtime.h>
#include <hip/hip_bf16.h>

// DeepSeek-V3 MoE, GPTQ int4 experts, fp32 baseline (round 1).
// Strategy: exploit top-4 sparsity (coeff==0 exactly for unselected experts),
// gather tokens per expert, fp32 vector FMA (no fp32 MFMA on CDNA4).
// Predicted: ~1.0ms, VALUBusy>75%, MfmaUtil 0, HBM <10% peak.

#define T_TOK 1024
#define H_DIM 2048
#define I_DIM 1408
#define E_NUM 32
#define ISH   2816
#define HW_   (H_DIM/8)   // 256 words per gate/up row
#define HG_   (H_DIM/128) // 16 groups
#define IW_   (I_DIM/8)   // 176 words per down row
#define IG_   (I_DIM/128) // 11 groups

#define COMP_I4(v,k) ((k)==0?(v).x:(k)==1?(v).y:(k)==2?(v).z:(v).w)
#define COMP_F4(v,k) ((k)==0?(v).x:(k)==1?(v).y:(k)==2?(v).z:(v).w)

__device__ __forceinline__ float sigmoidf_(float v) { return 1.f / (1.f + __expf(-v)); }

// ---------------- K1: router: scores, top-4, renorm, expert lists ----------------
__global__ __launch_bounds__(256)
void k_router(const float* __restrict__ x, const float* __restrict__ gw,
              int* __restrict__ counts, int* __restrict__ elist, float* __restrict__ ecoef)
{
    const int t = blockIdx.x;
    const int tid = threadIdx.x;
    const int e = tid & 31, seg = tid >> 5;
    const float* xr = x + (size_t)t * H_DIM;

    float p = 0.f;
    for (int k = 0; k < 256; ++k) {
        const int h = seg * 256 + k;
        p = fmaf(xr[h], gw[h * E_NUM + e], p);
    }
    __shared__ float ps[8][32];
    __shared__ float sc[32];
    ps[seg][e] = p;
    __syncthreads();
    if (tid < 32) {
        float s = 0.f;
        #pragma unroll
        for (int g = 0; g < 8; ++g) s += ps[g][tid];
        sc[tid] = sigmoidf_(s);
    }
    __syncthreads();
    if (tid == 0) {
        unsigned used = 0; float ssum = 0.f;
        int   sel[4]; float sv[4];
        for (int k = 0; k < 4; ++k) {
            float best = -1.f; int bi = 0;
            for (int e2 = 0; e2 < 32; ++e2) {
                if (used & (1u << e2)) continue;
                if (sc[e2] > best) { best = sc[e2]; bi = e2; }  // ties -> lower index (matches top_k)
            }
            used |= 1u << bi; sel[k] = bi; sv[k] = best; ssum += best;
        }
        const float inv = 2.5f / (ssum + 1e-20f);
        for (int k = 0; k < 4; ++k) {
            const int ee = sel[k];
            const int pos = atomicAdd(&counts[ee], 1);
            elist[ee * T_TOK + pos] = t | (k << 20);
            ecoef[ee * T_TOK + pos] = sv[k] * inv;
        }
    }
}

// ---------------- K2: routed gate/up dequant-GEMM + SwiGLU -> h_buf ----------------
// tile: 64 gathered tokens x 128 i. 256 thr = 32 i-groups(x4 i) x 8 tok-groups(x8 tok).
__global__ __launch_bounds__(256)
void k_gateup(const float* __restrict__ x,
              const int* __restrict__ gqw, const int* __restrict__ gqz, const float* __restrict__ gsc,
              const int* __restrict__ uqw, const int* __restrict__ uqz, const float* __restrict__ usc,
              const int* __restrict__ counts, const int* __restrict__ elist,
              float* __restrict__ h_buf)
{
    const int e = blockIdx.z;
    const int ne = counts[e];
    const int t0 = blockIdx.y * 64;
    if (t0 >= ne) return;
    const int ibase = blockIdx.x * 128;
    const int tid = threadIdx.x;
    const int ig = tid & 31;
    const int tg = tid >> 5;
    const int i0 = ibase + ig * 4;

    __shared__ int   toks[64];
    __shared__ float xs[64 * 128];

    if (tid < 64) toks[tid] = (t0 + tid < ne) ? elist[e * T_TOK + t0 + tid] : -1;

    float gacc[8][4], uacc[8][4];
    #pragma unroll
    for (int j = 0; j < 8; ++j)
        #pragma unroll
        for (int q = 0; q < 4; ++q) { gacc[j][q] = 0.f; uacc[j][q] = 0.f; }

    for (int ch = 0; ch < 16; ++ch) {
        __syncthreads();
        {   // stage gathered x tile [64][128]
            const int c4 = tid & 31;
            const int r0 = tid >> 5;
            #pragma unroll
            for (int p = 0; p < 8; ++p) {
                const int r = r0 + p * 8;
                const int tk = toks[r];
                float4 v = make_float4(0.f, 0.f, 0.f, 0.f);
                if (tk >= 0) {
                    const int trow = tk & 0xFFFFF;
                    v = *(const float4*)(x + (size_t)trow * H_DIM + ch * 128 + c4 * 4);
                }
                *(float4*)(xs + r * 128 + c4 * 4) = v;
            }
        }
        __syncthreads();

        float gS[4], gZS[4], uS[4], uZS[4];
        #pragma unroll
        for (int q = 0; q < 4; ++q) {
            const int ridx = e * I_DIM + i0 + q;
            const float s  = gsc[ridx * HG_ + ch];
            gS[q] = s;  gZS[q] = (float)gqz[ridx * HG_ + ch] * s;
            const float su = usc[ridx * HG_ + ch];
            uS[q] = su; uZS[q] = (float)uqz[ridx * HG_ + ch] * su;
        }

        #pragma unroll
        for (int sc_ = 0; sc_ < 4; ++sc_) {
            int4 gwv[4], uwv[4];
            #pragma unroll
            for (int q = 0; q < 4; ++q) {
                const size_t ro = (size_t)(e * I_DIM + i0 + q) * HW_ + ch * 16 + sc_ * 4;
                gwv[q] = *(const int4*)(gqw + ro);
                uwv[q] = *(const int4*)(uqw + ro);
            }
            #pragma unroll
            for (int w = 0; w < 4; ++w) {
                #pragma unroll
                for (int hf = 0; hf < 2; ++hf) {
                    const int cb = sc_ * 32 + w * 8 + hf * 4;
                    float4 xv[8];
                    #pragma unroll
                    for (int j = 0; j < 8; ++j)
                        xv[j] = *(const float4*)(xs + (tg * 8 + j) * 128 + cb);
                    #pragma unroll
                    for (int q = 0; q < 4; ++q) {
                        const int gwd = COMP_I4(gwv[q], w);
                        const int uwd = COMP_I4(uwv[q], w);
                        float gc[4], uc[4];
                        #pragma unroll
                        for (int b = 0; b < 4; ++b) {
                            const int sh = hf * 16 + b * 4;
                            gc[b] = fmaf((float)((gwd >> sh) & 0xF), gS[q], -gZS[q]);
                            uc[b] = fmaf((float)((uwd >> sh) & 0xF), uS[q], -uZS[q]);
                        }
                        #pragma unroll
                        for (int j = 0; j < 8; ++j) {
                            const float4 xx = xv[j];
                            gacc[j][q] = fmaf(gc[0], xx.x, gacc[j][q]);
                            gacc[j][q] = fmaf(gc[1], xx.y, gacc[j][q]);
                            gacc[j][q] = fmaf(gc[2], xx.z, gacc[j][q]);
                            gacc[j][q] = fmaf(gc[3], xx.w, gacc[j][q]);
                            uacc[j][q] = fmaf(uc[0], xx.x, uacc[j][q]);
                            uacc[j][q] = fmaf(uc[1], xx.y, uacc[j][q]);
                            uacc[j][q] = fmaf(uc[2], xx.z, uacc[j][q]);
                            uacc[j][q] = fmaf(uc[3], xx.w, uacc[j][q]);
                        }
                    }
                }
            }
        }
    }
    #pragma unroll
    for (int j = 0; j < 8; ++j) {
        const int r = tg * 8 + j;
        const int tk = toks[r];
        if (tk < 0) continue;
        const int trow = tk & 0xFFFFF;
        const int slot = tk >> 20;
        float4 hv;
        float g;
        g = gacc[j][0]; hv.x = g * sigmoidf_(g) * uacc[j][0];
        g = gacc[j][1]; hv.y = g * sigmoidf_(g) * uacc[j][1];
        g = gacc[j][2]; hv.z = g * sigmoidf_(g) * uacc[j][2];
        g = gacc[j][3]; hv.w = g * sigmoidf_(g) * uacc[j][3];
        *(float4*)(h_buf + (size_t)(trow * 4 + slot) * I_DIM + i0) = hv;
    }
}

// ---------------- K3: routed down dequant-GEMM, atomic combine into out ----------------
__global__ __launch_bounds__(256)
void k_down(const float* __restrict__ h_buf,
            const int* __restrict__ dqw, const int* __restrict__ dqz, const float* __restrict__ dsc,
            const int* __restrict__ counts, const int* __restrict__ elist, const float* __restrict__ ecoef,
            float* __restrict__ out)
{
    const int e = blockIdx.z;
    const int ne = counts[e];
    const int t0 = blockIdx.y * 64;
    if (t0 >= ne) return;
    const int hbase = blockIdx.x * 128;
    const int tid = threadIdx.x;
    const int hg = tid & 31;
    const int tg = tid >> 5;
    const int h0 = hbase + hg * 4;

    __shared__ int   toks[64];
    __shared__ float cofs[64];
    __shared__ float xs[64 * 128];

    if (tid < 64) {
        const bool v = (t0 + tid < ne);
        toks[tid] = v ? elist[e * T_TOK + t0 + tid] : -1;
        cofs[tid] = v ? ecoef[e * T_TOK + t0 + tid] : 0.f;
    }

    float acc[8][4];
    #pragma unroll
    for (int j = 0; j < 8; ++j)
        #pragma unroll
        for (int q = 0; q < 4; ++q) acc[j][q] = 0.f;

    for (int ch = 0; ch < 11; ++ch) {
        __syncthreads();
        {
            const int c4 = tid & 31;
            const int r0 = tid >> 5;
            #pragma unroll
            for (int p = 0; p < 8; ++p) {
                const int r = r0 + p * 8;
                const int tk = toks[r];
                float4 v = make_float4(0.f, 0.f, 0.f, 0.f);
                if (tk >= 0) {
                    const int row = (tk & 0xFFFFF) * 4 + (tk >> 20);
                    v = *(const float4*)(h_buf + (size_t)row * I_DIM + ch * 128 + c4 * 4);
                }
                *(float4*)(xs + r * 128 + c4 * 4) = v;
            }
        }
        __syncthreads();

        float S[4], ZS[4];
        #pragma unroll
        for (int q = 0; q < 4; ++q) {
            const int ridx = e * H_DIM + h0 + q;
            const float s = dsc[ridx * IG_ + ch];
            S[q] = s; ZS[q] = (float)dqz[ridx * IG_ + ch] * s;
        }

        #pragma unroll
        for (int sc_ = 0; sc_ < 4; ++sc_) {
            int4 wv[4];
            #pragma unroll
            for (int q = 0; q < 4; ++q)
                wv[q] = *(const int4*)(dqw + (size_t)(e * H_DIM + h0 + q) * IW_ + ch * 16 + sc_ * 4);
            #pragma unroll
            for (int w = 0; w < 4; ++w) {
                #pragma unroll
                for (int hf = 0; hf < 2; ++hf) {
                    const int cb = sc_ * 32 + w * 8 + hf * 4;
                    float4 xv[8];
                    #pragma unroll
                    for (int j = 0; j < 8; ++j)
                        xv[j] = *(const float4*)(xs + (tg * 8 + j) * 128 + cb);
                    #pragma unroll
                    for (int q = 0; q < 4; ++q) {
                        const int wd = COMP_I4(wv[q], w);
                        float wc[4];
                        #pragma unroll
                        for (int b = 0; b < 4; ++b) {
                            const int sh = hf * 16 + b * 4;
                            wc[b] = fmaf((float)((wd >> sh) & 0xF), S[q], -ZS[q]);
                        }
                        #pragma unroll
                        for (int j = 0; j < 8; ++j) {
                            const float4 xx = xv[j];
                            acc[j][q] = fmaf(wc[0], xx.x, acc[j][q]);
                            acc[j][q] = fmaf(wc[1], xx.y, acc[j][q]);
                            acc[j][q] = fmaf(wc[2], xx.z, acc[j][q]);
                            acc[j][q] = fmaf(wc[3], xx.w, acc[j][q]);
                        }
                    }
                }
            }
        }
    }
    #pragma unroll
    for (int j = 0; j < 8; ++j) {
        const int r = tg * 8 + j;
        const int tk = toks[r];
        if (tk < 0) continue;
        const int trow = tk & 0xFFFFF;
        const float c = cofs[r];
        #pragma unroll
        for (int q = 0; q < 4; ++q)
            atomicAdd(out + (size_t)trow * H_DIM + h0 + q, c * acc[j][q]);
    }
}

// ---------------- K4: shared gate/up SwiGLU -> hs ----------------
// tile: 32 tokens x 128 j. 256 thr = 32 j-groups(x4) x 8 tok-groups(x4 tok).
__global__ __launch_bounds__(256)
void k_shared_gu(const float* __restrict__ x, const float* __restrict__ gwp, const float* __restrict__ uwp,
                 float* __restrict__ hs)
{
    const int t0 = blockIdx.y * 32;
    const int jbase = blockIdx.x * 128;
    const int tid = threadIdx.x;
    const int jg = tid & 31;
    const int tg = tid >> 5;
    const int j0 = jbase + jg * 4;

    __shared__ float xs[32 * 128];
    float gacc[4][4], uacc[4][4];
    #pragma unroll
    for (int j = 0; j < 4; ++j)
        #pragma unroll
        for (int q = 0; q < 4; ++q) { gacc[j][q] = 0.f; uacc[j][q] = 0.f; }

    for (int ch = 0; ch < 16; ++ch) {
        __syncthreads();
        {
            const int c4 = tid & 31;
            const int r0 = tid >> 5;
            #pragma unroll
            for (int p = 0; p < 4; ++p) {
                const int r = r0 + p * 8;
                *(float4*)(xs + r * 128 + c4 * 4) =
                    *(const float4*)(x + (size_t)(t0 + r) * H_DIM + ch * 128 + c4 * 4);
            }
        }
        __syncthreads();
        #pragma unroll 4
        for (int hq = 0; hq < 32; ++hq) {
            float4 xv[4];
            #pragma unroll
            for (int j = 0; j < 4; ++j)
                xv[j] = *(const float4*)(xs + (tg * 4 + j) * 128 + hq * 4);
            #pragma unroll
            for (int k = 0; k < 4; ++k) {
                const int hrow = ch * 128 + hq * 4 + k;
                const float4 wg = *(const float4*)(gwp + (size_t)hrow * ISH + j0);
                const float4 wu = *(const float4*)(uwp + (size_t)hrow * ISH + j0);
                #pragma unroll
                for (int j = 0; j < 4; ++j) {
                    const float xx = COMP_F4(xv[j], k);
                    gacc[j][0] = fmaf(wg.x, xx, gacc[j][0]);
                    gacc[j][1] = fmaf(wg.y, xx, gacc[j][1]);
                    gacc[j][2] = fmaf(wg.z, xx, gacc[j][2]);
                    gacc[j][3] = fmaf(wg.w, xx, gacc[j][3]);
                    uacc[j][0] = fmaf(wu.x, xx, uacc[j][0]);
                    uacc[j][1] = fmaf(wu.y, xx, uacc[j][1]);
                    uacc[j][2] = fmaf(wu.z, xx, uacc[j][2]);
                    uacc[j][3] = fmaf(wu.w, xx, uacc[j][3]);
                }
            }
        }
    }
    #pragma unroll
    for (int j = 0; j < 4; ++j) {
        const int t = t0 + tg * 4 + j;
        float4 hv; float g;
        g = gacc[j][0]; hv.x = g * sigmoidf_(g) * uacc[j][0];
        g = gacc[j][1]; hv.y = g * sigmoidf_(g) * uacc[j][1];
        g = gacc[j][2]; hv.z = g * sigmoidf_(g) * uacc[j][2];
        g = gacc[j][3]; hv.w = g * sigmoidf_(g) * uacc[j][3];
        *(float4*)(hs + (size_t)t * ISH + j0) = hv;
    }
}

// ---------------- K5: shared down -> writes out (initializes it) ----------------
__global__ __launch_bounds__(256)
void k_shared_down(const float* __restrict__ hs, const float* __restrict__ dwp, float* __restrict__ out)
{
    const int t0 = blockIdx.y * 32;
    const int hbase = blockIdx.x * 128;
    const int tid = threadIdx.x;
    const int hg = tid & 31;
    const int tg = tid >> 5;
    const int h0 = hbase + hg * 4;

    __shared__ float xs[32 * 128];
    float acc[4][4];
    #pragma unroll
    for (int j = 0; j < 4; ++j)
        #pragma unroll
        for (int q = 0; q < 4; ++q) acc[j][q] = 0.f;

    for (int ch = 0; ch < 22; ++ch) {
        __syncthreads();
        {
            const int c4 = tid & 31;
            const int r0 = tid >> 5;
            #pragma unroll
            for (int p = 0; p < 4; ++p) {
                const int r = r0 + p * 8;
                *(float4*)(xs + r * 128 + c4 * 4) =
                    *(const float4*)(hs + (size_t)(t0 + r) * ISH + ch * 128 + c4 * 4);
            }
        }
        __syncthreads();
        #pragma unroll 4
        for (int iq = 0; iq < 32; ++iq) {
            float4 xv[4];
            #pragma unroll
            for (int j = 0; j < 4; ++j)
                xv[j] = *(const float4*)(xs + (tg * 4 + j) * 128 + iq * 4);
            #pragma unroll
            for (int k = 0; k < 4; ++k) {
                const int irow = ch * 128 + iq * 4 + k;
                const float4 wv = *(const float4*)(dwp + (size_t)irow * H_DIM + h0);
                #pragma unroll
                for (int j = 0; j < 4; ++j) {
                    const float xx = COMP_F4(xv[j], k);
                    acc[j][0] = fmaf(wv.x, xx, acc[j][0]);
                    acc[j][1] = fmaf(wv.y, xx, acc[j][1]);
                    acc[j][2] = fmaf(wv.z, xx, acc[j][2]);
                    acc[j][3] = fmaf(wv.w, xx, acc[j][3]);
                }
            }
        }
    }
    #pragma unroll
    for (int j = 0; j < 4; ++j) {
        const int t = t0 + tg * 4 + j;
        float4 ov;
        ov.x = acc[j][0]; ov.y = acc[j][1]; ov.z = acc[j][2]; ov.w = acc[j][3];
        *(float4*)(out + (size_t)t * H_DIM + h0) = ov;
    }
}

extern "C" void kernel_launch(void* const* d_in, const int* in_sizes, int n_in,
                              void* d_out, int out_size, void* d_ws, size_t ws_size,
                              hipStream_t stream)
{
    const float* x   = (const float*)d_in[0];
    const float* gw  = (const float*)d_in[1];
    const int*   gqw = (const int*)d_in[2];
    const int*   gqz = (const int*)d_in[3];
    const float* gsc = (const float*)d_in[4];
    const int*   uqw = (const int*)d_in[5];
    const int*   uqz = (const int*)d_in[6];
    const float* usc = (const float*)d_in[7];
    const int*   dqw = (const int*)d_in[8];
    const int*   dqz = (const int*)d_in[9];
    const float* dsc = (const float*)d_in[10];
    const float* sgw = (const float*)d_in[11];
    const float* suw = (const float*)d_in[12];
    const float* sdw = (const float*)d_in[13];
    float* out = (float*)d_out;

    char* ws = (char*)d_ws;
    int*   counts = (int*)ws;                                   // 32 ints
    int*   elist  = (int*)(ws + 1024);                          // 32*1024 ints
    float* ecoef  = (float*)(ws + 1024 + 131072);               // 32*1024 floats
    float* h_buf  = (float*)(ws + 1024 + 2 * 131072);           // 1024*4*1408 floats (23 MB)
    float* hs     = h_buf + (size_t)T_TOK * 4 * I_DIM;          // 1024*2816 floats (11.5 MB)

    hipMemsetAsync(counts, 0, E_NUM * sizeof(int), stream);
    k_router<<<dim3(T_TOK), 256, 0, stream>>>(x, gw, counts, elist, ecoef);
    k_gateup<<<dim3(I_DIM / 128, T_TOK / 64, E_NUM), 256, 0, stream>>>(
        x, gqw, gqz, gsc, uqw, uqz, usc, counts, elist, h_buf);
    k_shared_gu<<<dim3(ISH / 128, T_TOK / 32), 256, 0, stream>>>(x, sgw, suw, hs);
    k_shared_down<<<dim3(H_DIM / 128, T_TOK / 32), 256, 0, stream>>>(hs, sdw, out);
    k_down<<<dim3(H_DIM / 128, T_TOK / 64, E_NUM), 256, 0, stream>>>(
        h_buf, dqw, dqz, dsc, counts, elist, ecoef, out);
}

// Round 2
// 636.390 us; speedup vs baseline: 6.5268x; 6.5268x over previous
//
#include <hip/hip_runtime.h>
#include <hip/hip_fp16.h>

// DeepSeek-V3 MoE w/ GPTQ int4 experts — round 2: f16 MFMA everywhere.
// Codes exact in f16 via 0x6400|c bias trick; (c-z)*s premultiplied into
// B-frags so one MFMA acc chain spans all K. x/h/shared-W rounded to f16.

#define T_TOK 1024
#define H_DIM 2048
#define I_DIM 1408
#define E_NUM 32
#define ISH   2816

typedef _Float16 f16_t;
typedef f16_t f16x8 __attribute__((ext_vector_type(8)));
typedef float f32x16 __attribute__((ext_vector_type(16)));

__device__ __forceinline__ uint32_t h2_u32(__half2 h) { union { __half2 h; uint32_t u; } c; c.h = h; return c.u; }
__device__ __forceinline__ __half2 u32_h2(uint32_t u) { union { uint32_t u; __half2 h; } c; c.u = u; return c.h; }

// codes pair (bits0-3, bits4-7 of t) -> f16x2 of (c-z)*s
__device__ __forceinline__ uint32_t unpack_pair(uint32_t t, uint32_t z2, uint32_t s2) {
    uint32_t m = 0x64006400u | (t & 0xFu) | ((t & 0xF0u) << 12);   // (1024+c0, 1024+c1)
    __half2 h = __hsub2(u32_h2(m), u32_h2(z2));                    // exact (c-z)
    h = __hmul2(h, u32_h2(s2));
    return h2_u32(h);
}

__device__ __forceinline__ f16x8 unpack_frag(uint32_t w, uint32_t z2, uint32_t s2) {
    union { uint32_t u[4]; f16x8 v; } r;
    r.u[0] = unpack_pair(w, z2, s2);
    r.u[1] = unpack_pair(w >> 8, z2, s2);
    r.u[2] = unpack_pair(w >> 16, z2, s2);
    r.u[3] = unpack_pair(w >> 24, z2, s2);
    return r.v;
}

// routed staging chunk permutation (matches paired-int4 weight loads)
__device__ __forceinline__ int perm_routed(int u) { return ((u & 3) << 1) | ((u >> 2) & 1) | (u & 8); }
// shared staging chunk permutation (matches contiguous f16 weight loads)
__device__ __forceinline__ int perm_shared(int u) { return ((u & 7) << 1) | (u >> 3); }

__device__ __forceinline__ float sigmoidf_(float v) { return 1.f / (1.f + __expf(-v)); }

// ---------------- prep: x f32 -> f16 ----------------
__global__ __launch_bounds__(256)
void k_cvt(const float* __restrict__ in, __half* __restrict__ outp)
{
    const int i = blockIdx.x * 256 + threadIdx.x;   // 8 elems each
    const float4 a = *(const float4*)(in + (size_t)i * 8);
    const float4 b = *(const float4*)(in + (size_t)i * 8 + 4);
    int4 o;
    o.x = h2_u32(__floats2half2_rn(a.x, a.y));
    o.y = h2_u32(__floats2half2_rn(a.z, a.w));
    o.z = h2_u32(__floats2half2_rn(b.x, b.y));
    o.w = h2_u32(__floats2half2_rn(b.z, b.w));
    *(int4*)(outp + (size_t)i * 8) = o;
}

// ---------------- prep: transpose f32 [R][C] -> f16 [C][R] ----------------
__global__ __launch_bounds__(256)
void k_tr(const float* __restrict__ in, __half* __restrict__ outp, int R, int C)
{
    __shared__ float tile[32][33];
    const int tx = threadIdx.x & 31, ty = threadIdx.x >> 5;
    const int cx = blockIdx.x * 32 + tx;
    #pragma unroll
    for (int j = 0; j < 4; ++j) {
        const int ry = blockIdx.y * 32 + ty + j * 8;
        tile[ty + j * 8][tx] = in[(size_t)ry * C + cx];
    }
    __syncthreads();
    const int ox = blockIdx.y * 32 + tx;
    #pragma unroll
    for (int j = 0; j < 4; ++j) {
        const int oy = blockIdx.x * 32 + ty + j * 8;
        outp[(size_t)oy * R + ox] = __float2half(tile[tx][ty + j * 8]);
    }
}

// ---------------- router (f32, exact top-4 semantics) ----------------
__global__ __launch_bounds__(256)
void k_router(const float* __restrict__ x, const float* __restrict__ gw,
              int* __restrict__ counts, int* __restrict__ elist, float* __restrict__ ecoef)
{
    const int t = blockIdx.x;
    const int tid = threadIdx.x;
    const int e = tid & 31, seg = tid >> 5;
    const float* xr = x + (size_t)t * H_DIM;
    float p = 0.f;
    for (int k = 0; k < 256; ++k)
        p = fmaf(xr[seg * 256 + k], gw[(seg * 256 + k) * E_NUM + e], p);
    __shared__ float ps[8][32];
    __shared__ float sc[32];
    ps[seg][e] = p;
    __syncthreads();
    if (tid < 32) {
        float s = 0.f;
        #pragma unroll
        for (int g = 0; g < 8; ++g) s += ps[g][tid];
        sc[tid] = sigmoidf_(s);
    }
    __syncthreads();
    if (tid == 0) {
        unsigned used = 0; float ssum = 0.f;
        int sel[4]; float sv[4];
        for (int k = 0; k < 4; ++k) {
            float best = -1.f; int bi = 0;
            for (int e2 = 0; e2 < 32; ++e2) {
                if (used & (1u << e2)) continue;
                if (sc[e2] > best) { best = sc[e2]; bi = e2; }
            }
            used |= 1u << bi; sel[k] = bi; sv[k] = best; ssum += best;
        }
        const float inv = 2.5f / (ssum + 1e-20f);
        for (int k = 0; k < 4; ++k) {
            const int ee = sel[k];
            const int pos = atomicAdd(&counts[ee], 1);
            elist[ee * T_TOK + pos] = t | (k << 20);
            ecoef[ee * T_TOK + pos] = sv[k] * inv;
        }
    }
}

// ---------------- routed gate/up: 64 tok x 128 i, MFMA f16 ----------------
__global__ __launch_bounds__(256)
void k_gateup(const __half* __restrict__ xq,
              const int* __restrict__ gqw, const int* __restrict__ gqz, const float* __restrict__ gsc,
              const int* __restrict__ uqw, const int* __restrict__ uqz, const float* __restrict__ usc,
              const int* __restrict__ counts, const int* __restrict__ elist, const float* __restrict__ ecoef,
              __half* __restrict__ h_buf)
{
    const int e = blockIdx.z;
    const int ne = counts[e];
    const int t0 = blockIdx.y * 64;
    if (t0 >= ne) return;
    const int tid = threadIdx.x;
    const int lane = tid & 63;
    const int wv = tid >> 6;
    const int li = lane & 31;
    const int c  = lane >> 5;
    const int i_col = blockIdx.x * 128 + wv * 32 + li;

    __shared__ int   toks[64];
    __shared__ float cofs[64];
    __shared__ __align__(16) char xs[64 * 256];

    if (tid < 64) {
        const bool v = (t0 + tid) < ne;
        toks[tid] = v ? elist[e * T_TOK + t0 + tid] : -1;
        cofs[tid] = v ? ecoef[e * T_TOK + t0 + tid] : 0.f;
    }

    f32x16 ag0, ag1, au0, au1;
    #pragma unroll
    for (int i = 0; i < 16; ++i) { ag0[i] = 0.f; ag1[i] = 0.f; au0[i] = 0.f; au1[i] = 0.f; }

    const size_t wrow = (size_t)(e * I_DIM + i_col);
    const int* gwr = gqw + wrow * 256;
    const int* uwr = uqw + wrow * 256;
    const int* gzr = gqz + wrow * 16;
    const int* uzr = uqz + wrow * 16;
    const float* gsr = gsc + wrow * 16;
    const float* usr = usc + wrow * 16;

    const int srow = tid >> 2;
    const int sq   = tid & 3;

    for (int g = 0; g < 16; ++g) {
        __syncthreads();
        {
            const int tk = toks[srow];
            const __half* src = (tk >= 0) ? (xq + (size_t)(tk & 0xFFFFF) * H_DIM + g * 128) : nullptr;
            #pragma unroll
            for (int cu = 0; cu < 4; ++cu) {
                const int u = sq * 4 + cu;
                int4 d = make_int4(0, 0, 0, 0);
                if (src) d = *(const int4*)(src + u * 8);
                *(int4*)(xs + srow * 256 + ((perm_routed(u) * 16) ^ ((srow & 7) << 4))) = d;
            }
        }
        __syncthreads();

        const int4 g1 = *(const int4*)(gwr + g * 16 + 4 * c);
        const int4 g2 = *(const int4*)(gwr + g * 16 + 8 + 4 * c);
        const int4 u1 = *(const int4*)(uwr + g * 16 + 4 * c);
        const int4 u2 = *(const int4*)(uwr + g * 16 + 8 + 4 * c);
        const uint32_t gz2 = 0x64006400u | ((uint32_t)gzr[g] * 0x10001u);
        const uint32_t uz2 = 0x64006400u | ((uint32_t)uzr[g] * 0x10001u);
        const uint32_t gs2 = h2_u32(__float2half2_rn(gsr[g]));
        const uint32_t us2 = h2_u32(__float2half2_rn(usr[g]));
        const uint32_t gwv[8] = {(uint32_t)g1.x,(uint32_t)g1.y,(uint32_t)g1.z,(uint32_t)g1.w,
                                 (uint32_t)g2.x,(uint32_t)g2.y,(uint32_t)g2.z,(uint32_t)g2.w};
        const uint32_t uwv[8] = {(uint32_t)u1.x,(uint32_t)u1.y,(uint32_t)u1.z,(uint32_t)u1.w,
                                 (uint32_t)u2.x,(uint32_t)u2.y,(uint32_t)u2.z,(uint32_t)u2.w};
        #pragma unroll
        for (int m = 0; m < 8; ++m) {
            const f16x8 bg = unpack_frag(gwv[m], gz2, gs2);
            const f16x8 bu = unpack_frag(uwv[m], uz2, us2);
            const int slotb = (2 * m + c) * 16;
            const f16x8 a0 = *(const f16x8*)(xs + li * 256 + (slotb ^ ((li & 7) << 4)));
            const f16x8 a1 = *(const f16x8*)(xs + (32 + li) * 256 + (slotb ^ ((li & 7) << 4)));
            ag0 = __builtin_amdgcn_mfma_f32_32x32x16_f16(a0, bg, ag0, 0, 0, 0);
            au0 = __builtin_amdgcn_mfma_f32_32x32x16_f16(a0, bu, au0, 0, 0, 0);
            ag1 = __builtin_amdgcn_mfma_f32_32x32x16_f16(a1, bg, ag1, 0, 0, 0);
            au1 = __builtin_amdgcn_mfma_f32_32x32x16_f16(a1, bu, au1, 0, 0, 0);
        }
    }

    #pragma unroll
    for (int r = 0; r < 16; ++r) {
        const int row0 = (r & 3) + 8 * (r >> 2) + 4 * c;
        {
            const int tk = toks[row0];
            if (tk >= 0) {
                const float gv = ag0[r], uv = au0[r];
                const float h = gv * sigmoidf_(gv) * uv * cofs[row0];
                h_buf[(size_t)((tk & 0xFFFFF) * 4 + (tk >> 20)) * I_DIM + i_col] = __float2half(h);
            }
        }
        {
            const int tk = toks[32 + row0];
            if (tk >= 0) {
                const float gv = ag1[r], uv = au1[r];
                const float h = gv * sigmoidf_(gv) * uv * cofs[32 + row0];
                h_buf[(size_t)((tk & 0xFFFFF) * 4 + (tk >> 20)) * I_DIM + i_col] = __float2half(h);
            }
        }
    }
}

// ---------------- routed down: 64 slot-rows x 128 h, atomic into out ----------------
__global__ __launch_bounds__(256)
void k_down(const __half* __restrict__ h_buf,
            const int* __restrict__ dqw, const int* __restrict__ dqz, const float* __restrict__ dsc,
            const int* __restrict__ counts, const int* __restrict__ elist,
            float* __restrict__ out)
{
    const int e = blockIdx.z;
    const int ne = counts[e];
    const int t0 = blockIdx.y * 64;
    if (t0 >= ne) return;
    const int tid = threadIdx.x;
    const int lane = tid & 63;
    const int wv = tid >> 6;
    const int li = lane & 31;
    const int c  = lane >> 5;
    const int h_col = blockIdx.x * 128 + wv * 32 + li;

    __shared__ int toks[64];
    __shared__ __align__(16) char xs[64 * 256];

    if (tid < 64) toks[tid] = ((t0 + tid) < ne) ? elist[e * T_TOK + t0 + tid] : -1;

    f32x16 a0, a1;
    #pragma unroll
    for (int i = 0; i < 16; ++i) { a0[i] = 0.f; a1[i] = 0.f; }

    const size_t wrow = (size_t)(e * H_DIM + h_col);
    const int* dwr = dqw + wrow * 176;
    const int* dzr = dqz + wrow * 11;
    const float* dsr = dsc + wrow * 11;

    const int srow = tid >> 2;
    const int sq   = tid & 3;

    for (int g = 0; g < 11; ++g) {
        __syncthreads();
        {
            const int tk = toks[srow];
            const __half* src = (tk >= 0)
                ? (h_buf + (size_t)((tk & 0xFFFFF) * 4 + (tk >> 20)) * I_DIM + g * 128) : nullptr;
            #pragma unroll
            for (int cu = 0; cu < 4; ++cu) {
                const int u = sq * 4 + cu;
                int4 d = make_int4(0, 0, 0, 0);
                if (src) d = *(const int4*)(src + u * 8);
                *(int4*)(xs + srow * 256 + ((perm_routed(u) * 16) ^ ((srow & 7) << 4))) = d;
            }
        }
        __syncthreads();

        const int4 w1 = *(const int4*)(dwr + g * 16 + 4 * c);
        const int4 w2 = *(const int4*)(dwr + g * 16 + 8 + 4 * c);
        const uint32_t z2 = 0x64006400u | ((uint32_t)dzr[g] * 0x10001u);
        const uint32_t s2 = h2_u32(__float2half2_rn(dsr[g]));
        const uint32_t wv8[8] = {(uint32_t)w1.x,(uint32_t)w1.y,(uint32_t)w1.z,(uint32_t)w1.w,
                                 (uint32_t)w2.x,(uint32_t)w2.y,(uint32_t)w2.z,(uint32_t)w2.w};
        #pragma unroll
        for (int m = 0; m < 8; ++m) {
            const f16x8 b = unpack_frag(wv8[m], z2, s2);
            const int slotb = (2 * m + c) * 16;
            const f16x8 x0 = *(const f16x8*)(xs + li * 256 + (slotb ^ ((li & 7) << 4)));
            const f16x8 x1 = *(const f16x8*)(xs + (32 + li) * 256 + (slotb ^ ((li & 7) << 4)));
            a0 = __builtin_amdgcn_mfma_f32_32x32x16_f16(x0, b, a0, 0, 0, 0);
            a1 = __builtin_amdgcn_mfma_f32_32x32x16_f16(x1, b, a1, 0, 0, 0);
        }
    }

    #pragma unroll
    for (int r = 0; r < 16; ++r) {
        const int row0 = (r & 3) + 8 * (r >> 2) + 4 * c;
        {
            const int tk = toks[row0];
            if (tk >= 0) atomicAdd(out + (size_t)(tk & 0xFFFFF) * H_DIM + h_col, a0[r]);
        }
        {
            const int tk = toks[32 + row0];
            if (tk >= 0) atomicAdd(out + (size_t)(tk & 0xFFFFF) * H_DIM + h_col, a1[r]);
        }
    }
}

// ---------------- shared gate/up: 64 tok x 128 n ----------------
__global__ __launch_bounds__(256)
void k_shared_gu(const __half* __restrict__ xq, const __half* __restrict__ wgt,
                 const __half* __restrict__ wut, __half* __restrict__ hs)
{
    const int t0 = blockIdx.y * 64;
    const int tid = threadIdx.x;
    const int lane = tid & 63;
    const int wv = tid >> 6;
    const int li = lane & 31;
    const int c  = lane >> 5;
    const int ncol = blockIdx.x * 128 + wv * 32 + li;

    __shared__ __align__(16) char xs[64 * 256];

    f32x16 ag0, ag1, au0, au1;
    #pragma unroll
    for (int i = 0; i < 16; ++i) { ag0[i] = 0.f; ag1[i] = 0.f; au0[i] = 0.f; au1[i] = 0.f; }

    const __half* gr = wgt + (size_t)ncol * H_DIM;
    const __half* ur = wut + (size_t)ncol * H_DIM;
    const int srow = tid >> 2;
    const int sq   = tid & 3;

    for (int g = 0; g < 16; ++g) {
        __syncthreads();
        {
            const __half* src = xq + (size_t)(t0 + srow) * H_DIM + g * 128;
            #pragma unroll
            for (int cu = 0; cu < 4; ++cu) {
                const int u = sq * 4 + cu;
                const int4 d = *(const int4*)(src + u * 8);
                *(int4*)(xs + srow * 256 + ((perm_shared(u) * 16) ^ ((srow & 7) << 4))) = d;
            }
        }
        __syncthreads();

        #pragma unroll
        for (int m = 0; m < 8; ++m) {
            const f16x8 bg = *(const f16x8*)(gr + g * 128 + c * 64 + m * 8);
            const f16x8 bu = *(const f16x8*)(ur + g * 128 + c * 64 + m * 8);
            const int slotb = (2 * m + c) * 16;
            const f16x8 a0 = *(const f16x8*)(xs + li * 256 + (slotb ^ ((li & 7) << 4)));
            const f16x8 a1 = *(const f16x8*)(xs + (32 + li) * 256 + (slotb ^ ((li & 7) << 4)));
            ag0 = __builtin_amdgcn_mfma_f32_32x32x16_f16(a0, bg, ag0, 0, 0, 0);
            au0 = __builtin_amdgcn_mfma_f32_32x32x16_f16(a0, bu, au0, 0, 0, 0);
            ag1 = __builtin_amdgcn_mfma_f32_32x32x16_f16(a1, bg, ag1, 0, 0, 0);
            au1 = __builtin_amdgcn_mfma_f32_32x32x16_f16(a1, bu, au1, 0, 0, 0);
        }
    }

    #pragma unroll
    for (int r = 0; r < 16; ++r) {
        const int row0 = (r & 3) + 8 * (r >> 2) + 4 * c;
        {
            const float gv = ag0[r], uv = au0[r];
            hs[(size_t)(t0 + row0) * ISH + ncol] = __float2half(gv * sigmoidf_(gv) * uv);
        }
        {
            const float gv = ag1[r], uv = au1[r];
            hs[(size_t)(t0 + 32 + row0) * ISH + ncol] = __float2half(gv * sigmoidf_(gv) * uv);
        }
    }
}

// ---------------- shared down: 64 tok x 128 h -> writes out ----------------
__global__ __launch_bounds__(256)
void k_shared_down(const __half* __restrict__ hs, const __half* __restrict__ wdt,
                   float* __restrict__ out)
{
    const int t0 = blockIdx.y * 64;
    const int tid = threadIdx.x;
    const int lane = tid & 63;
    const int wv = tid >> 6;
    const int li = lane & 31;
    const int c  = lane >> 5;
    const int hcol = blockIdx.x * 128 + wv * 32 + li;

    __shared__ __align__(16) char xs[64 * 256];

    f32x16 a0, a1;
    #pragma unroll
    for (int i = 0; i < 16; ++i) { a0[i] = 0.f; a1[i] = 0.f; }

    const __half* dr = wdt + (size_t)hcol * ISH;
    const int srow = tid >> 2;
    const int sq   = tid & 3;

    for (int g = 0; g < 22; ++g) {
        __syncthreads();
        {
            const __half* src = hs + (size_t)(t0 + srow) * ISH + g * 128;
            #pragma unroll
            for (int cu = 0; cu < 4; ++cu) {
                const int u = sq * 4 + cu;
                const int4 d = *(const int4*)(src + u * 8);
                *(int4*)(xs + srow * 256 + ((perm_shared(u) * 16) ^ ((srow & 7) << 4))) = d;
            }
        }
        __syncthreads();

        #pragma unroll
        for (int m = 0; m < 8; ++m) {
            const f16x8 b = *(const f16x8*)(dr + g * 128 + c * 64 + m * 8);
            const int slotb = (2 * m + c) * 16;
            const f16x8 x0 = *(const f16x8*)(xs + li * 256 + (slotb ^ ((li & 7) << 4)));
            const f16x8 x1 = *(const f16x8*)(xs + (32 + li) * 256 + (slotb ^ ((li & 7) << 4)));
            a0 = __builtin_amdgcn_mfma_f32_32x32x16_f16(x0, b, a0, 0, 0, 0);
            a1 = __builtin_amdgcn_mfma_f32_32x32x16_f16(x1, b, a1, 0, 0, 0);
        }
    }

    #pragma unroll
    for (int r = 0; r < 16; ++r) {
        const int row0 = (r & 3) + 8 * (r >> 2) + 4 * c;
        out[(size_t)(t0 + row0) * H_DIM + hcol] = a0[r];
        out[(size_t)(t0 + 32 + row0) * H_DIM + hcol] = a1[r];
    }
}

extern "C" void kernel_launch(void* const* d_in, const int* in_sizes, int n_in,
                              void* d_out, int out_size, void* d_ws, size_t ws_size,
                              hipStream_t stream)
{
    const float* x   = (const float*)d_in[0];
    const float* gw  = (const float*)d_in[1];
    const int*   gqw = (const int*)d_in[2];
    const int*   gqz = (const int*)d_in[3];
    const float* gsc = (const float*)d_in[4];
    const int*   uqw = (const int*)d_in[5];
    const int*   uqz = (const int*)d_in[6];
    const float* usc = (const float*)d_in[7];
    const int*   dqw = (const int*)d_in[8];
    const int*   dqz = (const int*)d_in[9];
    const float* dsc = (const float*)d_in[10];
    const float* sgw = (const float*)d_in[11];
    const float* suw = (const float*)d_in[12];
    const float* sdw = (const float*)d_in[13];
    float* out = (float*)d_out;

    char* ws = (char*)d_ws;
    constexpr size_t OFF_COUNTS = 0;
    constexpr size_t OFF_ELIST  = 1024;
    constexpr size_t OFF_ECOEF  = OFF_ELIST + (size_t)E_NUM * T_TOK * 4;
    constexpr size_t OFF_XQ     = OFF_ECOEF + (size_t)E_NUM * T_TOK * 4;
    constexpr size_t OFF_WGT    = OFF_XQ + (size_t)T_TOK * H_DIM * 2;
    constexpr size_t OFF_WUT    = OFF_WGT + (size_t)ISH * H_DIM * 2;
    constexpr size_t OFF_WDT    = OFF_WUT + (size_t)ISH * H_DIM * 2;
    constexpr size_t OFF_HBUF   = OFF_WDT + (size_t)H_DIM * ISH * 2;
    constexpr size_t OFF_HS     = OFF_HBUF + (size_t)T_TOK * 4 * I_DIM * 2;

    int*    counts = (int*)(ws + OFF_COUNTS);
    int*    elist  = (int*)(ws + OFF_ELIST);
    float*  ecoef  = (float*)(ws + OFF_ECOEF);
    __half* xq     = (__half*)(ws + OFF_XQ);
    __half* wgt    = (__half*)(ws + OFF_WGT);
    __half* wut    = (__half*)(ws + OFF_WUT);
    __half* wdt    = (__half*)(ws + OFF_WDT);
    __half* h_buf  = (__half*)(ws + OFF_HBUF);
    __half* hs     = (__half*)(ws + OFF_HS);

    hipMemsetAsync(counts, 0, E_NUM * sizeof(int), stream);
    k_cvt<<<dim3((T_TOK * H_DIM / 8) / 256), 256, 0, stream>>>(x, xq);
    k_tr<<<dim3(ISH / 32, H_DIM / 32), 256, 0, stream>>>(sgw, wgt, H_DIM, ISH);
    k_tr<<<dim3(ISH / 32, H_DIM / 32), 256, 0, stream>>>(suw, wut, H_DIM, ISH);
    k_tr<<<dim3(H_DIM / 32, ISH / 32), 256, 0, stream>>>(sdw, wdt, ISH, H_DIM);
    k_router<<<dim3(T_TOK), 256, 0, stream>>>(x, gw, counts, elist, ecoef);
    k_gateup<<<dim3(I_DIM / 128, T_TOK / 64, E_NUM), 256, 0, stream>>>(
        xq, gqw, gqz, gsc, uqw, uqz, usc, counts, elist, ecoef, h_buf);
    k_shared_gu<<<dim3(ISH / 128, T_TOK / 64), 256, 0, stream>>>(xq, wgt, wut, hs);
    k_shared_down<<<dim3(H_DIM / 128, T_TOK / 64), 256, 0, stream>>>(hs, wdt, out);
    k_down<<<dim3(H_DIM / 128, T_TOK / 64, E_NUM), 256, 0, stream>>>(
        h_buf, dqw, dqz, dsc, counts, elist, out);
}